// Round 17
// baseline (250.188 us; speedup 1.0000x reference)
//
#include <hip/hip_runtime.h>
#include <hip/hip_bf16.h>
#include <math.h>

#define NB   1024    // key blocks per batch
#define HKH  8       // Hk
#define NPROD 512    // producer threads (8 waves)

typedef float f4 __attribute__((ext_vector_type(4)));

// ---------------- Kernel Q: query gate projection -----------------
__global__ __launch_bounds__(512) void qproj_kernel(const float* __restrict__ q,
                                                    const float* __restrict__ Wq,
                                                    const float* __restrict__ qnw,
                                                    const float* __restrict__ cq,
                                                    const float* __restrict__ sq,
                                                    float* __restrict__ qv) {
    int b = blockIdx.x >> 3, h = blockIdx.x & 7;
    int t = threadIdx.x;
    int o = t & 127, seg = t >> 7;
    __shared__ float qs[512];
    __shared__ float part[4][128];
    __shared__ float red[2];
    __shared__ float ybuf[128];
    qs[t] = q[(size_t)b * 4096 + (size_t)h * 512 + t];
    __syncthreads();
    const float* wqp = Wq + (size_t)h * 512 * 128 + o;
    float acc = 0.0f;
    int g0 = seg * 128;
#pragma unroll 4
    for (int gi = g0; gi < g0 + 128; ++gi)
        acc = fmaf(qs[gi], wqp[(size_t)gi * 128], acc);
    part[seg][o] = acc;
    __syncthreads();
    if (t < 128) {
        float a = part[0][o] + part[1][o] + part[2][o] + part[3][o];
        ybuf[o] = a;
        float ss = a * a;
        for (int off = 32; off > 0; off >>= 1) ss += __shfl_xor(ss, off);
        if ((o & 63) == 0) red[o >> 6] = ss;
    }
    __syncthreads();
    if (t < 128) {
        float scale = rsqrtf((red[0] + red[1]) * (1.0f / 128.0f) + 1e-6f);
        float y  = ybuf[o] * scale * qnw[o];
        int op   = (o < 64) ? o + 64 : o - 64;
        float yp = ybuf[op] * scale * qnw[op];
        float rot = (o < 64) ? -yp : yp;
        qv[((size_t)b * HKH + h) * 128 + o] =
            fmaf(y, cq[b * 128 + o], rot * sq[b * 128 + o]);
    }
}

// ---------------- Fused producer/consumer kernel (2 wg/CU) ------------------
// grid = 512 wg (2/CU), 768 threads, LDS 64KB/wg. wg owns 8 consecutive
// key-blocks (2MB) as 2 tiles/LDS slots. Waves 0-7 (producers): NT streaming
// + register pooling (identical to R16). Waves 8-11 (consumers): R17 change —
// PER-SLOT M=4 GEMM passes: slot-0 pass starts as soon as slot 0 is ready
// (overlaps slot-1 streaming, ~90us of slack), slot-1 pass is the only
// exposed tail (~5us vs R16's full M=8 pass). W L2 traffic doubles but Wk
// stays L2-resident (k is NT — R10 ablation) and L2 BW has headroom.
__global__ __launch_bounds__(768) void fused_kernel(const float* __restrict__ kin,
                                                    const float* __restrict__ Wk,
                                                    const float* __restrict__ knw,
                                                    const float* __restrict__ cosk,
                                                    const float* __restrict__ sink,
                                                    const float* __restrict__ qv,
                                                    float* __restrict__ scores) {
    __shared__ float At[2][256][32];   // [slot][k][(h^g)*4 + bi], g=(k>>3)&7
    __shared__ int produced[2];
    int wg  = blockIdx.x;
    int b   = wg >> 7;
    int grp = wg & 127;                // blocks 8*grp .. 8*grp+7
    int t   = threadIdx.x;

    if (t < 2) produced[t] = 0;
    __syncthreads();

    if (t < NPROD) {
        // ================= PRODUCER (identical to R16) =================
        int col = t & 255;             // f4-col within 1024-float row
        int h   = col >> 5;
        int c   = col & 31;
        int bihalf = t >> 8;           // 0 -> blocks {0,2}, 1 -> {1,3}
        const float inv = 1.0f / 64.0f;
        for (int it = 0; it < 2; ++it) {
#pragma unroll
            for (int bb2 = 0; bb2 < 2; ++bb2) {
                int bi = bihalf + bb2 * 2;
                size_t row0 = (size_t)b * 65536 +
                              ((size_t)grp * 8 + it * 4 + bi) * 64;
                const f4* src = (const f4*)kin + row0 * 256 + col;
                f4 s = {0.f, 0.f, 0.f, 0.f};
                f4 m = {-3.4e38f, -3.4e38f, -3.4e38f, -3.4e38f};
#pragma unroll 8
                for (int r = 0; r < 64; ++r) {
                    f4 u = __builtin_nontemporal_load(src + (size_t)r * 256);
                    s += u;
                    m.x = fmaxf(m.x, u.x); m.y = fmaxf(m.y, u.y);
                    m.z = fmaxf(m.z, u.z); m.w = fmaxf(m.w, u.w);
                }
#pragma unroll
                for (int j = 0; j < 4; ++j) {
                    int k0 = c * 4 + j;
                    int g  = (k0 >> 3) & 7;
                    At[it][k0      ][((h ^ g) << 2) | bi] = s[j] * inv;
                    At[it][k0 + 128][((h ^ g) << 2) | bi] = m[j];
                }
            }
            __threadfence_block();
            atomicAdd(&produced[it], 1);
        }
    } else {
        // ================= CONSUMER: per-slot M=4 passes =================
        int tc = t - NPROD;
        int h  = tc >> 5;
        int c  = tc & 31;              // cols 4c..4c+3 of head h
        const float* wp = Wk + (size_t)h * 32768 + c * 4;
        f4 kn  = *(const f4*)(knw + c * 4);
        f4 qvr = *(const f4*)(qv + ((size_t)b * HKH + h) * 128 + c * 4);
        volatile int* vfl = (volatile int*)produced;

#pragma unroll
        for (int sl = 0; sl < 2; ++sl) {
            while (vfl[sl] < NPROD) __builtin_amdgcn_s_sleep(2);
            __threadfence_block();

            float acc[4][4];
#pragma unroll
            for (int i = 0; i < 4; ++i)
#pragma unroll
                for (int j = 0; j < 4; ++j) acc[i][j] = 0.0f;

#pragma unroll 4
            for (int k = 0; k < 256; ++k) {
                int g = (k >> 3) & 7;
                f4 w = *(const f4*)(wp + (size_t)k * 128);     // coalesced L2
                f4 a = *(const f4*)&At[sl][k][(h ^ g) << 2];   // broadcast
#pragma unroll
                for (int i = 0; i < 4; ++i) {
                    acc[i][0] = fmaf(a[i], w.x, acc[i][0]);
                    acc[i][1] = fmaf(a[i], w.y, acc[i][1]);
                    acc[i][2] = fmaf(a[i], w.z, acc[i][2]);
                    acc[i][3] = fmaf(a[i], w.w, acc[i][3]);
                }
            }

            // epilogue: per-row rmsnorm + rope + dot(qv); 4 rows
#pragma unroll
            for (int i = 0; i < 4; ++i) {
                int blkg = grp * 8 + sl * 4 + i;
                float ss = 0.0f;
#pragma unroll
                for (int j = 0; j < 4; ++j) ss = fmaf(acc[i][j], acc[i][j], ss);
#pragma unroll
                for (int off = 1; off < 32; off <<= 1) ss += __shfl_xor(ss, off);
                float scale = rsqrtf(ss * (1.0f / 128.0f) + 1e-6f);
                f4 cb = *(const f4*)(cosk + ((size_t)b * NB + blkg) * 128 + c * 4);
                f4 sb = *(const f4*)(sink + ((size_t)b * NB + blkg) * 128 + c * 4);
                float part = 0.0f;
#pragma unroll
                for (int j = 0; j < 4; ++j) {
                    float y  = acc[i][j] * scale * kn[j];
                    float yp = __shfl_xor(y, 16);   // col partner o +/- 64
                    float rot = (c < 16) ? -yp : yp;
                    float z = fmaf(y, cb[j], rot * sb[j]);
                    part = fmaf(z, qvr[j], part);
                }
#pragma unroll
                for (int off = 1; off < 32; off <<= 1) part += __shfl_xor(part, off);
                if (c == 0)
                    scores[((size_t)b * HKH + h) * NB + blkg] =
                        part * 0.08838834764831845f;
            }
        }
    }
}

// ---------------- Kernel D: rank-by-counting top-k -> int32 mask ----------
__device__ inline bool read_mask(const void* amp, int mode, size_t idx) {
    if (mode == 1) return ((const int*)amp)[idx] != 0;
    if (mode == 2) return ((const unsigned int*)amp)[idx] != 0u;
    return ((const unsigned char*)amp)[idx] != 0;
}

__global__ __launch_bounds__(512) void topk_kernel(const float* __restrict__ scores,
                                                   const void* __restrict__ amraw,
                                                   const int* __restrict__ bbp,
                                                   int* __restrict__ out) {
    int b = blockIdx.x >> 3, h = blockIdx.x & 7;
    int t = threadIdx.x;
    __shared__ float sv[NB];
    __shared__ int mode_sh;

    if (t == 0) {
        const unsigned int* w = (const unsigned int*)amraw;
        bool allint = true, allflt = true;
        for (int i = 0; i < 64; ++i) {
            unsigned int x = w[i];
            if (x != 0u && x != 1u) allint = false;
            if (x != 0u && x != 0x3f800000u) allflt = false;
        }
        mode_sh = allint ? 1 : (allflt ? 2 : 0);
    }
    __syncthreads();
    int mode = mode_sh;
    size_t rowoff = ((size_t)b * HKH + h) * NB;
    const float* src = scores + rowoff;
    for (int s = t; s < NB; s += 512)
        sv[s] = read_mask(amraw, mode, rowoff + s) ? src[s] : -1e20f;
    __syncthreads();

    int bb = bbp[0];
    if (bb > NB) bb = NB;
    if (bb < 1)  bb = 1;

    int e0 = t, e1 = t + 512;
    float v0 = sv[e0], v1 = sv[e1];
    int r0 = 0, r1 = 0;   // rank = #gt + #eq-at-lower-index
#pragma unroll 4
    for (int j4 = 0; j4 < 256; ++j4) {
        f4 w = *(const f4*)&sv[j4 * 4];
        int jb = j4 * 4;
        r0 += (w.x > v0) + (w.y > v0) + (w.z > v0) + (w.w > v0);
        r1 += (w.x > v1) + (w.y > v1) + (w.z > v1) + (w.w > v1);
        r0 += (w.x == v0 && jb + 0 < e0) + (w.y == v0 && jb + 1 < e0)
            + (w.z == v0 && jb + 2 < e0) + (w.w == v0 && jb + 3 < e0);
        r1 += (w.x == v1 && jb + 0 < e1) + (w.y == v1 && jb + 1 < e1)
            + (w.z == v1 && jb + 2 < e1) + (w.w == v1 && jb + 3 < e1);
    }
    int* dst = out + rowoff;
    bool am0 = read_mask(amraw, mode, rowoff + e0);
    bool am1 = read_mask(amraw, mode, rowoff + e1);
    dst[e0] = ((r0 < bb && am0)) ? 1 : 0;
    dst[e1] = ((r1 < bb && am1) || (e1 == NB - 1)) ? 1 : 0;
}

extern "C" void kernel_launch(void* const* d_in, const int* in_sizes, int n_in,
                              void* d_out, int out_size, void* d_ws, size_t ws_size,
                              hipStream_t stream) {
    (void)in_sizes; (void)n_in; (void)out_size; (void)ws_size;
    const float* k   = (const float*)d_in[0];
    const float* q   = (const float*)d_in[1];
    const float* Wq  = (const float*)d_in[2];
    const float* Wk  = (const float*)d_in[3];
    const float* qnw = (const float*)d_in[4];
    const float* knw = (const float*)d_in[5];
    const float* cq  = (const float*)d_in[6];
    const float* sq  = (const float*)d_in[7];
    const float* ck  = (const float*)d_in[8];
    const float* sk  = (const float*)d_in[9];
    const void*  am  = d_in[10];
    const int*   bb  = (const int*)d_in[11];
    int* out = (int*)d_out;

    float* qv     = (float*)d_ws;                 // 4*8*128 floats
    float* scores = qv + 4 * HKH * 128;           // 4*8*1024 floats

    qproj_kernel<<<32, 512, 0, stream>>>(q, Wq, qnw, cq, sq, qv);
    fused_kernel<<<512, 768, 0, stream>>>(k, Wk, knw, ck, sk, qv, scores);
    topk_kernel<<<32, 512, 0, stream>>>(scores, am, bb, out);
}

// Round 18
// 238.463 us; speedup vs baseline: 1.0492x; 1.0492x over previous
//
#include <hip/hip_runtime.h>
#include <hip/hip_bf16.h>
#include <math.h>

#define NB   1024    // key blocks per batch
#define HKH  8       // Hk
#define NPROD 512    // producer threads (8 waves)

typedef float f4 __attribute__((ext_vector_type(4)));

// ---------------- Kernel Q: query gate projection -----------------
// grid = B*HK = 32 blocks, 1024 threads (8-way K split per output dim) —
// latency-bound kernel; more TLP to hide serial FMA chains + cold Wq misses.
__global__ __launch_bounds__(1024) void qproj_kernel(const float* __restrict__ q,
                                                     const float* __restrict__ Wq,
                                                     const float* __restrict__ qnw,
                                                     const float* __restrict__ cq,
                                                     const float* __restrict__ sq,
                                                     float* __restrict__ qv) {
    int b = blockIdx.x >> 3, h = blockIdx.x & 7;
    int t = threadIdx.x;
    int o = t & 127, seg = t >> 7;     // seg 0..7
    __shared__ float qs[512];
    __shared__ float part[8][128];
    __shared__ float red[2];
    __shared__ float ybuf[128];
    if (t < 512) qs[t] = q[(size_t)b * 4096 + (size_t)h * 512 + t];
    __syncthreads();
    const float* wqp = Wq + (size_t)h * 512 * 128 + o;
    float acc = 0.0f;
    int g0 = seg * 64;
#pragma unroll 4
    for (int gi = g0; gi < g0 + 64; ++gi)
        acc = fmaf(qs[gi], wqp[(size_t)gi * 128], acc);
    part[seg][o] = acc;
    __syncthreads();
    if (t < 128) {
        float a = 0.0f;
#pragma unroll
        for (int s8 = 0; s8 < 8; ++s8) a += part[s8][o];
        ybuf[o] = a;
        float ss = a * a;
        for (int off = 32; off > 0; off >>= 1) ss += __shfl_xor(ss, off);
        if ((o & 63) == 0) red[o >> 6] = ss;
    }
    __syncthreads();
    if (t < 128) {
        float scale = rsqrtf((red[0] + red[1]) * (1.0f / 128.0f) + 1e-6f);
        float y  = ybuf[o] * scale * qnw[o];
        int op   = (o < 64) ? o + 64 : o - 64;
        float yp = ybuf[op] * scale * qnw[op];
        float rot = (o < 64) ? -yp : yp;
        qv[((size_t)b * HKH + h) * 128 + o] =
            fmaf(y, cq[b * 128 + o], rot * sq[b * 128 + o]);
    }
}

// ---------------- Fused producer/consumer kernel (2 wg/CU) — R16 exact ------
// grid = 512 wg (2/CU), 768 threads, LDS 64KB/wg. wg owns 8 consecutive
// key-blocks (2MB) as 2 tiles/LDS slots. Waves 0-7 (producers): NT streaming
// + register pooling. Waves 8-11 (consumers): ONE M=8 GEMM pass over slots
// {0,1} (8 rows per W b128 — best W-reuse; R17 showed splitting loses) +
// rmsnorm/rope/qdot epilogue. 16 streaming waves/CU early window.
__global__ __launch_bounds__(768) void fused_kernel(const float* __restrict__ kin,
                                                    const float* __restrict__ Wk,
                                                    const float* __restrict__ knw,
                                                    const float* __restrict__ cosk,
                                                    const float* __restrict__ sink,
                                                    const float* __restrict__ qv,
                                                    float* __restrict__ scores) {
    __shared__ float At[2][256][32];   // [slot][k][(h^g)*4 + bi], g=(k>>3)&7
    __shared__ int produced[2];
    int wg  = blockIdx.x;
    int b   = wg >> 7;
    int grp = wg & 127;                // blocks 8*grp .. 8*grp+7
    int t   = threadIdx.x;

    if (t < 2) produced[t] = 0;
    __syncthreads();

    if (t < NPROD) {
        // ================= PRODUCER =================
        int col = t & 255;             // f4-col within 1024-float row
        int h   = col >> 5;
        int c   = col & 31;
        int bihalf = t >> 8;           // 0 -> blocks {0,2}, 1 -> {1,3}
        const float inv = 1.0f / 64.0f;
        for (int it = 0; it < 2; ++it) {
#pragma unroll
            for (int bb2 = 0; bb2 < 2; ++bb2) {
                int bi = bihalf + bb2 * 2;
                size_t row0 = (size_t)b * 65536 +
                              ((size_t)grp * 8 + it * 4 + bi) * 64;
                const f4* src = (const f4*)kin + row0 * 256 + col;
                f4 s = {0.f, 0.f, 0.f, 0.f};
                f4 m = {-3.4e38f, -3.4e38f, -3.4e38f, -3.4e38f};
#pragma unroll 8
                for (int r = 0; r < 64; ++r) {
                    f4 u = __builtin_nontemporal_load(src + (size_t)r * 256);
                    s += u;
                    m.x = fmaxf(m.x, u.x); m.y = fmaxf(m.y, u.y);
                    m.z = fmaxf(m.z, u.z); m.w = fmaxf(m.w, u.w);
                }
#pragma unroll
                for (int j = 0; j < 4; ++j) {
                    int k0 = c * 4 + j;
                    int g  = (k0 >> 3) & 7;
                    At[it][k0      ][((h ^ g) << 2) | bi] = s[j] * inv;
                    At[it][k0 + 128][((h ^ g) << 2) | bi] = m[j];
                }
            }
            __threadfence_block();
            atomicAdd(&produced[it], 1);
        }
    } else {
        // ================= CONSUMER: one M=8 pass over slots {0,1} ==========
        int tc = t - NPROD;
        int h  = tc >> 5;
        int c  = tc & 31;              // cols 4c..4c+3 of head h
        const float* wp = Wk + (size_t)h * 32768 + c * 4;
        f4 kn  = *(const f4*)(knw + c * 4);
        f4 qvr = *(const f4*)(qv + ((size_t)b * HKH + h) * 128 + c * 4);
        volatile int* vfl = (volatile int*)produced;

        while (vfl[1] < NPROD) __builtin_amdgcn_s_sleep(2);
        __threadfence_block();

        float acc0[4][4], acc1[4][4];
#pragma unroll
        for (int i = 0; i < 4; ++i)
#pragma unroll
            for (int j = 0; j < 4; ++j) { acc0[i][j] = 0.0f; acc1[i][j] = 0.0f; }

#pragma unroll 4
        for (int k = 0; k < 256; ++k) {
            int g = (k >> 3) & 7;
            f4 w  = *(const f4*)(wp + (size_t)k * 128);     // coalesced L2
            f4 a0 = *(const f4*)&At[0][k][(h ^ g) << 2];    // broadcast
            f4 a1 = *(const f4*)&At[1][k][(h ^ g) << 2];
#pragma unroll
            for (int i = 0; i < 4; ++i) {
                acc0[i][0] = fmaf(a0[i], w.x, acc0[i][0]);
                acc0[i][1] = fmaf(a0[i], w.y, acc0[i][1]);
                acc0[i][2] = fmaf(a0[i], w.z, acc0[i][2]);
                acc0[i][3] = fmaf(a0[i], w.w, acc0[i][3]);
                acc1[i][0] = fmaf(a1[i], w.x, acc1[i][0]);
                acc1[i][1] = fmaf(a1[i], w.y, acc1[i][1]);
                acc1[i][2] = fmaf(a1[i], w.z, acc1[i][2]);
                acc1[i][3] = fmaf(a1[i], w.w, acc1[i][3]);
            }
        }

        // epilogue: per-row rmsnorm + rope + dot(qv); 8 rows
#pragma unroll
        for (int half = 0; half < 2; ++half) {
            float (*acc)[4] = half ? acc1 : acc0;
#pragma unroll
            for (int i = 0; i < 4; ++i) {
                int blkg = grp * 8 + half * 4 + i;
                float ss = 0.0f;
#pragma unroll
                for (int j = 0; j < 4; ++j) ss = fmaf(acc[i][j], acc[i][j], ss);
#pragma unroll
                for (int off = 1; off < 32; off <<= 1) ss += __shfl_xor(ss, off);
                float scale = rsqrtf(ss * (1.0f / 128.0f) + 1e-6f);
                f4 cb = *(const f4*)(cosk + ((size_t)b * NB + blkg) * 128 + c * 4);
                f4 sb = *(const f4*)(sink + ((size_t)b * NB + blkg) * 128 + c * 4);
                float part = 0.0f;
#pragma unroll
                for (int j = 0; j < 4; ++j) {
                    float y  = acc[i][j] * scale * kn[j];
                    float yp = __shfl_xor(y, 16);   // col partner o +/- 64
                    float rot = (c < 16) ? -yp : yp;
                    float z = fmaf(y, cb[j], rot * sb[j]);
                    part = fmaf(z, qvr[j], part);
                }
#pragma unroll
                for (int off = 1; off < 32; off <<= 1) part += __shfl_xor(part, off);
                if (c == 0)
                    scores[((size_t)b * HKH + h) * NB + blkg] =
                        part * 0.08838834764831845f;
            }
        }
    }
}

// ---------------- Kernel D: rank-by-counting top-k -> int32 mask ----------
__device__ inline bool read_mask(const void* amp, int mode, size_t idx) {
    if (mode == 1) return ((const int*)amp)[idx] != 0;
    if (mode == 2) return ((const unsigned int*)amp)[idx] != 0u;
    return ((const unsigned char*)amp)[idx] != 0;
}

__global__ __launch_bounds__(512) void topk_kernel(const float* __restrict__ scores,
                                                   const void* __restrict__ amraw,
                                                   const int* __restrict__ bbp,
                                                   int* __restrict__ out) {
    int b = blockIdx.x >> 3, h = blockIdx.x & 7;
    int t = threadIdx.x;
    __shared__ float sv[NB];
    __shared__ int mode_sh;

    if (t == 0) {
        const unsigned int* w = (const unsigned int*)amraw;
        bool allint = true, allflt = true;
        for (int i = 0; i < 64; ++i) {
            unsigned int x = w[i];
            if (x != 0u && x != 1u) allint = false;
            if (x != 0u && x != 0x3f800000u) allflt = false;
        }
        mode_sh = allint ? 1 : (allflt ? 2 : 0);
    }
    __syncthreads();
    int mode = mode_sh;
    size_t rowoff = ((size_t)b * HKH + h) * NB;
    const float* src = scores + rowoff;
    for (int s = t; s < NB; s += 512)
        sv[s] = read_mask(amraw, mode, rowoff + s) ? src[s] : -1e20f;
    __syncthreads();

    int bb = bbp[0];
    if (bb > NB) bb = NB;
    if (bb < 1)  bb = 1;

    int e0 = t, e1 = t + 512;
    float v0 = sv[e0], v1 = sv[e1];
    int r0 = 0, r1 = 0;   // rank = #gt + #eq-at-lower-index
#pragma unroll 4
    for (int j4 = 0; j4 < 256; ++j4) {
        f4 w = *(const f4*)&sv[j4 * 4];
        int jb = j4 * 4;
        r0 += (w.x > v0) + (w.y > v0) + (w.z > v0) + (w.w > v0);
        r1 += (w.x > v1) + (w.y > v1) + (w.z > v1) + (w.w > v1);
        r0 += (w.x == v0 && jb + 0 < e0) + (w.y == v0 && jb + 1 < e0)
            + (w.z == v0 && jb + 2 < e0) + (w.w == v0 && jb + 3 < e0);
        r1 += (w.x == v1 && jb + 0 < e1) + (w.y == v1 && jb + 1 < e1)
            + (w.z == v1 && jb + 2 < e1) + (w.w == v1 && jb + 3 < e1);
    }
    int* dst = out + rowoff;
    bool am0 = read_mask(amraw, mode, rowoff + e0);
    bool am1 = read_mask(amraw, mode, rowoff + e1);
    dst[e0] = ((r0 < bb && am0)) ? 1 : 0;
    dst[e1] = ((r1 < bb && am1) || (e1 == NB - 1)) ? 1 : 0;
}

extern "C" void kernel_launch(void* const* d_in, const int* in_sizes, int n_in,
                              void* d_out, int out_size, void* d_ws, size_t ws_size,
                              hipStream_t stream) {
    (void)in_sizes; (void)n_in; (void)out_size; (void)ws_size;
    const float* k   = (const float*)d_in[0];
    const float* q   = (const float*)d_in[1];
    const float* Wq  = (const float*)d_in[2];
    const float* Wk  = (const float*)d_in[3];
    const float* qnw = (const float*)d_in[4];
    const float* knw = (const float*)d_in[5];
    const float* cq  = (const float*)d_in[6];
    const float* sq  = (const float*)d_in[7];
    const float* ck  = (const float*)d_in[8];
    const float* sk  = (const float*)d_in[9];
    const void*  am  = d_in[10];
    const int*   bb  = (const int*)d_in[11];
    int* out = (int*)d_out;

    float* qv     = (float*)d_ws;                 // 4*8*128 floats
    float* scores = qv + 4 * HKH * 128;           // 4*8*1024 floats

    qproj_kernel<<<32, 1024, 0, stream>>>(q, Wq, qnw, cq, sq, qv);
    fused_kernel<<<512, 768, 0, stream>>>(k, Wk, knw, ck, sk, qv, scores);
    topk_kernel<<<32, 512, 0, stream>>>(scores, am, bb, out);
}